// Round 11
// baseline (208.979 us; speedup 1.0000x reference)
//
#include <hip/hip_runtime.h>
#include <hip/hip_bf16.h>

// MHA: x[2,2048,1024] f32 in, f32 out. 16 heads x 64, causal.
// Pipeline: convert -> FUSED QKV gemm (Q pre-scaled, V transposed) ->
// flash attention v11: ZERO-LDS, barrier-free. grid 2048 x 64 thr (1 wave
// per block; wave = 32 q-rows x ALL keys of its j). K/V fragments loaded
// straight from global (L2-resident, ~2MB/XCD; qh-pair waves share via L1)
// into register double-buffers; compiler's counted vmcnt pipelines loads
// across tiles. No barriers, no vmcnt coupling, no cross-wave combine --
// waves are fully independent streams (v9/v10 lesson: independent streams
// beat DS-ratio). CU-balanced j decode (each CU's 8 waves sum to 132
// tiles). Register P via the v7-verified permlane merge. -> proj gemm.

typedef __hip_bfloat16 bf16;
typedef __attribute__((ext_vector_type(8))) short short8;
typedef __attribute__((ext_vector_type(4))) short short4v;
typedef __attribute__((ext_vector_type(4))) float f32x4;
typedef __attribute__((ext_vector_type(2))) unsigned uint2v;
typedef __attribute__((ext_vector_type(4))) unsigned uint4v;

#define MFMA16(a, b, c) __builtin_amdgcn_mfma_f32_16x16x32_bf16((a), (b), (c), 0, 0, 0)

__device__ __forceinline__ void load_lds16(const void* g, void* l) {
  __builtin_amdgcn_global_load_lds(
      (const __attribute__((address_space(1))) void*)g,
      (__attribute__((address_space(3))) void*)l, 16, 0, 0);
}

// Q is pre-scaled by (1/8)*log2(e) so attention can use exp2 directly.
#define QSCALE 0.18033688f

// ---------------- f32 -> bf16 conversion (exact 1D grid: 8192 blocks) --------
__global__ __launch_bounds__(256) void cvt_kernel(
    const float* __restrict__ x, const float* __restrict__ wq,
    const float* __restrict__ wk, const float* __restrict__ wv,
    const float* __restrict__ wo, bf16* __restrict__ xb,
    bf16* __restrict__ wcat) {
  const int bx = blockIdx.x;
  const float* src;
  bf16* dst;
  int ib;
  if (bx < 4096) { src = x; dst = xb; ib = bx; }
  else {
    const int wseg = (bx - 4096) >> 10;
    ib = (bx - 4096) & 1023;
    src = wseg == 0 ? wq : wseg == 1 ? wk : wseg == 2 ? wv : wo;
    dst = wcat + (size_t)wseg * 1048576;
  }
  const int i = (ib * 256 + threadIdx.x) * 4;
  const float4 v = *(const float4*)(src + i);
  short4v p;
  *(__hip_bfloat162*)&p = __float22bfloat162_rn(float2{v.x, v.y});
  *((__hip_bfloat162*)&p + 1) = __float22bfloat162_rn(float2{v.z, v.w});
  *(short4v*)(dst + i) = p;
}

// ---------------- Fused QKV GEMM: [4096,1024] @ [3072,1024]^T ----------------
// 128x128 tile, BK=64, 4 waves 2x2. grid 768 (1-D, XCD-partitioned).
__global__ __launch_bounds__(256) void qkv_kernel(
    const bf16* __restrict__ x, const bf16* __restrict__ Wcat,
    const float* __restrict__ bq, const float* __restrict__ bk,
    const float* __restrict__ bv, bf16* __restrict__ Qb,
    bf16* __restrict__ Kb, bf16* __restrict__ Vtg) {
  constexpr int K = 1024;
  __shared__ bf16 As[128 * 64];
  __shared__ bf16 Bs[128 * 64];
  const int t = threadIdx.x;
  const int lane = t & 63, w = t >> 6;
  const int quad = lane >> 4, r = lane & 15;
  const int bid = blockIdx.x;               // 0..767
  const int xcd = bid & 7, idx = bid >> 3;  // idx 0..95
  const int nloc = idx % 3, my = idx / 3;   // my 0..31
  const int nx = xcd * 3 + nloc;            // 0..23
  const int m0 = my * 128;
  const int ncol = nx * 128;                // 0..2944
  const int seg = ncol >> 10;               // 0=Q, 1=K, 2=V
  const int n0 = ncol & 1023;
  const int wm = w >> 1, wn = w & 1;

  f32x4 acc[4][4] = {};

  for (int k0 = 0; k0 < K; k0 += 64) {
    __syncthreads();
#pragma unroll
    for (int p = 0; p < 4; ++p) {           // A: 1024 chunks
      const int c = p * 256 + w * 64 + lane;
      const int row = c >> 3;
      const int scb = (c & 7) ^ (row & 7);
      load_lds16(x + (size_t)(m0 + row) * K + k0 + scb * 8, As + c * 8);
    }
#pragma unroll
    for (int p = 0; p < 4; ++p) {           // B: 1024 chunks
      const int c = p * 256 + w * 64 + lane;
      const int row = c >> 3;
      const int scb = (c & 7) ^ (row & 7);
      load_lds16(Wcat + (size_t)(ncol + row) * K + k0 + scb * 8, Bs + c * 8);
    }
    __syncthreads();
    short8 af[4][2], bfr[4][2];
#pragma unroll
    for (int ks = 0; ks < 2; ++ks) {
#pragma unroll
      for (int i = 0; i < 4; ++i) {
        const int ra = wm * 64 + i * 16 + r;
        af[i][ks] = *(const short8*)(As + ra * 64 +
                                     (((ks * 4 + quad) ^ (ra & 7)) * 8));
        const int rb = wn * 64 + i * 16 + r;
        bfr[i][ks] = *(const short8*)(Bs + rb * 64 +
                                      (((ks * 4 + quad) ^ (rb & 7)) * 8));
      }
    }
#pragma unroll
    for (int ks = 0; ks < 2; ++ks)
#pragma unroll
      for (int i = 0; i < 4; ++i)
#pragma unroll
        for (int j = 0; j < 4; ++j)
          acc[i][j] = MFMA16(af[i][ks], bfr[j][ks], acc[i][j]);
  }

  const float* bias = seg == 0 ? bq : seg == 1 ? bk : bv;
  const float scale = seg == 0 ? QSCALE : 1.0f;
  bf16* dst01 = seg == 0 ? Qb : Kb;
#pragma unroll
  for (int i = 0; i < 4; ++i) {
    const int m = m0 + wm * 64 + i * 16 + quad * 4;
#pragma unroll
    for (int j = 0; j < 4; ++j) {
      const int nn = n0 + wn * 64 + j * 16 + r;
      const float bv_ = bias[nn];
      if (seg == 2) {                       // V: transposed packed store
        short4v pk;
        *(__hip_bfloat162*)&pk = __float22bfloat162_rn(
            float2{acc[i][j][0] + bv_, acc[i][j][1] + bv_});
        *((__hip_bfloat162*)&pk + 1) = __float22bfloat162_rn(
            float2{acc[i][j][2] + bv_, acc[i][j][3] + bv_});
        *(short4v*)(Vtg + (size_t)nn * 4096 + m) = pk;
      } else {
#pragma unroll
        for (int g = 0; g < 4; ++g)
          dst01[(size_t)(m + g) * 1024 + nn] =
              __float2bfloat16((acc[i][j][g] + bv_) * scale);
      }
    }
  }
}

// ---------------- proj GEMM: out[4096,1024] = Ob @ Wo^T + bo (f32 out) -------
__global__ __launch_bounds__(256) void proj_kernel(const bf16* __restrict__ X,
                                                   const bf16* __restrict__ W,
                                                   const float* __restrict__ bias,
                                                   float* __restrict__ Y) {
  constexpr int K = 1024, N = 1024;
  __shared__ bf16 As[64 * 64];
  __shared__ bf16 Bs[128 * 64];
  const int t = threadIdx.x;
  const int lane = t & 63, w = t >> 6;
  const int quad = lane >> 4, r = lane & 15;
  const int bid = blockIdx.x;               // 0..511
  const int xcd = bid & 7, idx = bid >> 3;  // idx 0..63
  const int m0 = idx * 64, n0 = xcd * 128;
  const int wm = w >> 1, wn = w & 1;

  f32x4 acc[2][4] = {};

  for (int k0 = 0; k0 < K; k0 += 64) {
    __syncthreads();
#pragma unroll
    for (int p = 0; p < 2; ++p) {           // A: 512 chunks
      const int c = p * 256 + w * 64 + lane;
      const int row = c >> 3;
      const int scb = (c & 7) ^ (row & 7);
      load_lds16(X + (size_t)(m0 + row) * K + k0 + scb * 8, As + c * 8);
    }
#pragma unroll
    for (int p = 0; p < 4; ++p) {           // B: 1024 chunks
      const int c = p * 256 + w * 64 + lane;
      const int row = c >> 3;
      const int scb = (c & 7) ^ (row & 7);
      load_lds16(W + (size_t)(n0 + row) * K + k0 + scb * 8, Bs + c * 8);
    }
    __syncthreads();
    short8 af[2][2], bfr[4][2];
#pragma unroll
    for (int ks = 0; ks < 2; ++ks) {
#pragma unroll
      for (int i = 0; i < 2; ++i) {
        const int ra = wm * 32 + i * 16 + r;
        af[i][ks] = *(const short8*)(As + ra * 64 +
                                     (((ks * 4 + quad) ^ (ra & 7)) * 8));
      }
#pragma unroll
      for (int j = 0; j < 4; ++j) {
        const int rb = wn * 64 + j * 16 + r;
        bfr[j][ks] = *(const short8*)(Bs + rb * 64 +
                                      (((ks * 4 + quad) ^ (rb & 7)) * 8));
      }
    }
#pragma unroll
    for (int ks = 0; ks < 2; ++ks)
#pragma unroll
      for (int i = 0; i < 2; ++i)
#pragma unroll
        for (int j = 0; j < 4; ++j)
          acc[i][j] = MFMA16(af[i][ks], bfr[j][ks], acc[i][j]);
  }
#pragma unroll
  for (int i = 0; i < 2; ++i) {
    const int m = m0 + wm * 32 + i * 16 + quad * 4;
#pragma unroll
    for (int j = 0; j < 4; ++j) {
      const int n = n0 + wn * 64 + j * 16 + r;
      const float bv = bias[n];
#pragma unroll
      for (int g = 0; g < 4; ++g)
        Y[(size_t)(m + g) * N + n] = acc[i][j][g] + bv;
    }
  }
}

// ---------------- Flash attention v11: zero-LDS register pipeline ------------
// grid 2048 x 64 thr (1 wave/block; wave = 32 q-rows x all keys of j).
// Decode: x=bid&7, u=(bid>>3)&31, k=bid>>8 (kk=k&3, qh=k>>2);
// g = x+8*kk (h=g&15, b=g>>4); j = {u,31-u,(u+8)&31,31-((u+8)&31)}[kk].
// Per CU (x,u): 8 waves, T sums to 132 (balanced); (j,qh=0/1) pairs on the
// same CU share K/V reads via L1; (h,b) pinned per XCD (L2-resident).
// Per tile: 8 kf + 8 vf global b128 loads (reg double-buffered), 16 S-MFMA
// + 16 PV-MFMA; v7-verified 4-group permlane merge for P; no barriers, no
// LDS, no combine. Compiler inserts counted vmcnt for the pipeline.
__global__ __launch_bounds__(64, 2) void attn_kernel(const bf16* __restrict__ Qb,
                                                     const bf16* __restrict__ Kb,
                                                     const bf16* __restrict__ Vtg,
                                                     bf16* __restrict__ Ob) {
  const int bid = blockIdx.x;
  const int x = bid & 7, u = (bid >> 3) & 31, k = bid >> 8;
  const int kk = k & 3, qh = k >> 2;
  const int g = x + 8 * kk;                 // 0..31
  const int h = g & 15, b = g >> 4;
  const int u8 = (u + 8) & 31;
  const int j = (kk == 0) ? u : (kk == 1) ? 31 - u : (kk == 2) ? u8 : 31 - u8;
  const int T = j + 1;

  const int lane = threadIdx.x & 63;
  const int quad = lane >> 4, r = lane & 15;

  // per-lane global fragment bases (bf16-element offsets)
  const size_t kbase = (size_t)b * 2048 * 1024 + (size_t)r * 1024 +
                       h * 64 + quad * 8;
  const size_t vbase = (size_t)(h * 64 + r) * 4096 + (size_t)b * 2048 +
                       quad * 8;

  auto loadK = [&](int tile, short8 (&kf)[4][2]) {
    const size_t tb = kbase + (size_t)tile * 65536;
#pragma unroll
    for (int mt2 = 0; mt2 < 4; ++mt2)
#pragma unroll
      for (int ks = 0; ks < 2; ++ks)
        kf[mt2][ks] = *(const short8*)(Kb + tb + mt2 * 16384 + ks * 32);
  };
  auto loadV = [&](int tile, short8 (&vf)[4][2]) {
    const size_t tb = vbase + tile * 64;
#pragma unroll
    for (int mt = 0; mt < 4; ++mt)
#pragma unroll
      for (int ksl = 0; ksl < 2; ++ksl)
        vf[mt][ksl] = *(const short8*)(Vtg + tb + mt * 65536 + ksl * 32);
  };

  // Q fragments (B-operand): [qfr][ks] for this wave's 32 q-rows
  const int qrow0 = j * 64 + qh * 32;       // + qfr*16 + r
  short8 qf[2][2];
#pragma unroll
  for (int qfr = 0; qfr < 2; ++qfr)
#pragma unroll
    for (int ks = 0; ks < 2; ++ks)
      qf[qfr][ks] = *(const short8*)(
          Qb + (size_t)(b * 2048 + qrow0 + qfr * 16 + r) * 1024 +
          h * 64 + ks * 32 + quad * 8);

  f32x4 o[4][2] = {};                       // [mt(d)][qfr]
  float lsum[2] = {0.f, 0.f};

  // one 64-key tile, fully in registers
  auto compute = [&](const short8 (&kf)[4][2], const short8 (&vf)[4][2],
                     int s) {
    // ---- S^T = K * Q^T : 64 keys x 32 q ----
    f32x4 st[4][2] = {};
#pragma unroll
    for (int mt2 = 0; mt2 < 4; ++mt2)
#pragma unroll
      for (int qfr = 0; qfr < 2; ++qfr) {
        st[mt2][qfr] = MFMA16(kf[mt2][0], qf[qfr][0], st[mt2][qfr]);
        st[mt2][qfr] = MFMA16(kf[mt2][1], qf[qfr][1], st[mt2][qfr]);
      }
    if (s == T - 1) {                       // diagonal tile mask
#pragma unroll
      for (int mt2 = 0; mt2 < 4; ++mt2)
#pragma unroll
        for (int qfr = 0; qfr < 2; ++qfr) {
          const int kb2 = s * 64 + mt2 * 16 + quad * 4;
          const int qrow = qrow0 + qfr * 16 + r;
#pragma unroll
          for (int g4 = 0; g4 < 4; ++g4)
            if (kb2 + g4 > qrow) st[mt2][qfr][g4] = -1e30f;
        }
    }
    // ---- softmax numerators + pack ----
    unsigned cpk[4][2][2];                  // [mt2][qfr][pair]
#pragma unroll
    for (int mt2 = 0; mt2 < 4; ++mt2)
#pragma unroll
      for (int qfr = 0; qfr < 2; ++qfr) {
        const float p0 = __builtin_amdgcn_exp2f(st[mt2][qfr][0]);
        const float p1 = __builtin_amdgcn_exp2f(st[mt2][qfr][1]);
        const float p2 = __builtin_amdgcn_exp2f(st[mt2][qfr][2]);
        const float p3 = __builtin_amdgcn_exp2f(st[mt2][qfr][3]);
        lsum[qfr] += (p0 + p1) + (p2 + p3);
        unsigned u0, u1;
        *(__hip_bfloat162*)&u0 = __float22bfloat162_rn(float2{p0, p1});
        *(__hip_bfloat162*)&u1 = __float22bfloat162_rn(float2{p2, p3});
        cpk[mt2][qfr][0] = u0;
        cpk[mt2][qfr][1] = u1;
      }
    // ---- register P -> PV B-frags via permlane merge (v7-verified) ----
    short8 pf[2][2];                        // [ksl][qfr]
#pragma unroll
    for (int ksl = 0; ksl < 2; ++ksl)
#pragma unroll
      for (int qfr = 0; qfr < 2; ++qfr) {
        unsigned br[4];
#pragma unroll
        for (int p2 = 0; p2 < 2; ++p2) {
          uint2v s32 = __builtin_amdgcn_permlane32_swap(
              cpk[ksl * 2][qfr][p2], cpk[ksl * 2 + 1][qfr][p2], false, false);
          uint2v s16 = __builtin_amdgcn_permlane16_swap(s32.x, s32.y,
                                                        false, false);
          br[p2] = s16.x; br[p2 + 2] = s16.y;
        }
        uint4v pv_; pv_.x = br[0]; pv_.y = br[1]; pv_.z = br[2]; pv_.w = br[3];
        pf[ksl][qfr] = __builtin_bit_cast(short8, pv_);
      }
    // ---- PV: O^T += V^T * P over all 64 keys ----
#pragma unroll
    for (int mt = 0; mt < 4; ++mt)
#pragma unroll
      for (int ksl = 0; ksl < 2; ++ksl)
#pragma unroll
        for (int qfr = 0; qfr < 2; ++qfr)
          o[mt][qfr] = MFMA16(vf[mt][ksl], pf[ksl][qfr], o[mt][qfr]);
  };

  short8 KA[4][2], KB[4][2], VA[4][2], VB[4][2];
  loadK(0, KA);
  loadV(0, VA);
  int s = 0;
  while (true) {
    if (s + 1 < T) { loadK(s + 1, KB); loadV(s + 1, VB); }
    compute(KA, VA, s);
    if (++s == T) break;
    if (s + 1 < T) { loadK(s + 1, KA); loadV(s + 1, VA); }
    compute(KB, VB, s);
    if (++s == T) break;
  }

  // ---- denominators (quad partials) + store ----
  float inv[2];
#pragma unroll
  for (int qfr = 0; qfr < 2; ++qfr) {
    float ls = lsum[qfr];
    ls += __shfl_xor(ls, 16);
    ls += __shfl_xor(ls, 32);
    inv[qfr] = 1.f / ls;
  }
#pragma unroll
  for (int mt = 0; mt < 4; ++mt)
#pragma unroll
    for (int qfr = 0; qfr < 2; ++qfr) {
      short4v ph;
      *(__hip_bfloat162*)&ph = __float22bfloat162_rn(
          float2{o[mt][qfr][0] * inv[qfr], o[mt][qfr][1] * inv[qfr]});
      *((__hip_bfloat162*)&ph + 1) = __float22bfloat162_rn(
          float2{o[mt][qfr][2] * inv[qfr], o[mt][qfr][3] * inv[qfr]});
      *(short4v*)(Ob + (size_t)(b * 2048 + qrow0 + qfr * 16 + r) * 1024 +
                  h * 64 + mt * 16 + quad * 4) = ph;
    }
}

extern "C" void kernel_launch(void* const* d_in, const int* in_sizes, int n_in,
                              void* d_out, int out_size, void* d_ws, size_t ws_size,
                              hipStream_t stream) {
  const float* x  = (const float*)d_in[0];
  const float* Wq = (const float*)d_in[1];
  const float* bq = (const float*)d_in[2];
  const float* Wk = (const float*)d_in[3];
  const float* bk = (const float*)d_in[4];
  const float* Wv = (const float*)d_in[5];
  const float* bv = (const float*)d_in[6];
  const float* Wo = (const float*)d_in[7];
  const float* bo = (const float*)d_in[8];
  float* out = (float*)d_out;

  bf16* xb   = (bf16*)d_ws;                     // 4M elems
  bf16* wcat = xb + (size_t)4096 * 1024;        // [wq|wk|wv|wo]
  bf16* wob  = wcat + (size_t)3 * 1024 * 1024;
  bf16* Qb   = wcat + (size_t)4 * 1024 * 1024;
  bf16* Kb   = Qb  + (size_t)4096 * 1024;
  bf16* Vtg  = Kb  + (size_t)4096 * 1024;       // V^T [1024][4096]
  bf16* Ob   = Vtg + (size_t)4096 * 1024;
  const size_t need = ((size_t)4096 * 1024 * 5 + (size_t)1024 * 1024 * 4) * 2;
  if (ws_size < need) return;

  cvt_kernel<<<8192, 256, 0, stream>>>(x, Wq, Wk, Wv, Wo, xb, wcat);
  qkv_kernel<<<768, 256, 0, stream>>>(xb, wcat, bq, bk, bv, Qb, Kb, Vtg);
  attn_kernel<<<2048, 64, 0, stream>>>(Qb, Kb, Vtg, Ob);
  proj_kernel<<<512, 256, 0, stream>>>(Ob, wob, bo, out);
}

// Round 12
// 167.184 us; speedup vs baseline: 1.2500x; 1.2500x over previous
//
#include <hip/hip_runtime.h>
#include <hip/hip_bf16.h>

// MHA: x[2,2048,1024] f32 in, f32 out. 16 heads x 64, causal.
// Pipeline: convert -> FUSED QKV gemm (Q pre-scaled, V transposed) ->
// flash attention v9 (best verified): UNPAIRED, CU-balanced. grid 1024 x
// 256thr (4 waves = 2 qs x 2 kst), one 64-q tile per block, 32KB LDS ->
// 4 blocks/CU = 16 waves/CU in 4 INDEPENDENT barrier groups. Decode
// exploits round-robin dispatch: each CU's 4 blocks have j summing to 66
// (perfect balance); each (h,b)'s K/V pinned to one XCD. Counted-vmcnt
// dbuf schedule; register P via permlane merge; 2-way kst combine.
// -> proj gemm. [v10 ratio-0.25 and v11 zero-LDS both falsified; this is
// the measured-best configuration: 170.2us e2e.]

typedef __hip_bfloat16 bf16;
typedef __attribute__((ext_vector_type(8))) short short8;
typedef __attribute__((ext_vector_type(4))) short short4v;
typedef __attribute__((ext_vector_type(4))) float f32x4;
typedef __attribute__((ext_vector_type(2))) unsigned uint2v;
typedef __attribute__((ext_vector_type(4))) unsigned uint4v;

#define MFMA16(a, b, c) __builtin_amdgcn_mfma_f32_16x16x32_bf16((a), (b), (c), 0, 0, 0)

__device__ __forceinline__ void load_lds16(const void* g, void* l) {
  __builtin_amdgcn_global_load_lds(
      (const __attribute__((address_space(1))) void*)g,
      (__attribute__((address_space(3))) void*)l, 16, 0, 0);
}

// Q is pre-scaled by (1/8)*log2(e) so attention can use exp2 directly.
#define QSCALE 0.18033688f

// ---------------- f32 -> bf16 conversion (exact 1D grid: 8192 blocks) --------
__global__ __launch_bounds__(256) void cvt_kernel(
    const float* __restrict__ x, const float* __restrict__ wq,
    const float* __restrict__ wk, const float* __restrict__ wv,
    const float* __restrict__ wo, bf16* __restrict__ xb,
    bf16* __restrict__ wcat) {
  const int bx = blockIdx.x;
  const float* src;
  bf16* dst;
  int ib;
  if (bx < 4096) { src = x; dst = xb; ib = bx; }
  else {
    const int wseg = (bx - 4096) >> 10;
    ib = (bx - 4096) & 1023;
    src = wseg == 0 ? wq : wseg == 1 ? wk : wseg == 2 ? wv : wo;
    dst = wcat + (size_t)wseg * 1048576;
  }
  const int i = (ib * 256 + threadIdx.x) * 4;
  const float4 v = *(const float4*)(src + i);
  short4v p;
  *(__hip_bfloat162*)&p = __float22bfloat162_rn(float2{v.x, v.y});
  *((__hip_bfloat162*)&p + 1) = __float22bfloat162_rn(float2{v.z, v.w});
  *(short4v*)(dst + i) = p;
}

// ---------------- Fused QKV GEMM: [4096,1024] @ [3072,1024]^T ----------------
// 128x128 tile, BK=64, 4 waves 2x2. grid 768 (1-D, XCD-partitioned).
__global__ __launch_bounds__(256) void qkv_kernel(
    const bf16* __restrict__ x, const bf16* __restrict__ Wcat,
    const float* __restrict__ bq, const float* __restrict__ bk,
    const float* __restrict__ bv, bf16* __restrict__ Qb,
    bf16* __restrict__ Kb, bf16* __restrict__ Vtg) {
  constexpr int K = 1024;
  __shared__ bf16 As[128 * 64];
  __shared__ bf16 Bs[128 * 64];
  const int t = threadIdx.x;
  const int lane = t & 63, w = t >> 6;
  const int quad = lane >> 4, r = lane & 15;
  const int bid = blockIdx.x;               // 0..767
  const int xcd = bid & 7, idx = bid >> 3;  // idx 0..95
  const int nloc = idx % 3, my = idx / 3;   // my 0..31
  const int nx = xcd * 3 + nloc;            // 0..23
  const int m0 = my * 128;
  const int ncol = nx * 128;                // 0..2944
  const int seg = ncol >> 10;               // 0=Q, 1=K, 2=V
  const int n0 = ncol & 1023;
  const int wm = w >> 1, wn = w & 1;

  f32x4 acc[4][4] = {};

  for (int k0 = 0; k0 < K; k0 += 64) {
    __syncthreads();
#pragma unroll
    for (int p = 0; p < 4; ++p) {           // A: 1024 chunks
      const int c = p * 256 + w * 64 + lane;
      const int row = c >> 3;
      const int scb = (c & 7) ^ (row & 7);
      load_lds16(x + (size_t)(m0 + row) * K + k0 + scb * 8, As + c * 8);
    }
#pragma unroll
    for (int p = 0; p < 4; ++p) {           // B: 1024 chunks
      const int c = p * 256 + w * 64 + lane;
      const int row = c >> 3;
      const int scb = (c & 7) ^ (row & 7);
      load_lds16(Wcat + (size_t)(ncol + row) * K + k0 + scb * 8, Bs + c * 8);
    }
    __syncthreads();
    short8 af[4][2], bfr[4][2];
#pragma unroll
    for (int ks = 0; ks < 2; ++ks) {
#pragma unroll
      for (int i = 0; i < 4; ++i) {
        const int ra = wm * 64 + i * 16 + r;
        af[i][ks] = *(const short8*)(As + ra * 64 +
                                     (((ks * 4 + quad) ^ (ra & 7)) * 8));
        const int rb = wn * 64 + i * 16 + r;
        bfr[i][ks] = *(const short8*)(Bs + rb * 64 +
                                      (((ks * 4 + quad) ^ (rb & 7)) * 8));
      }
    }
#pragma unroll
    for (int ks = 0; ks < 2; ++ks)
#pragma unroll
      for (int i = 0; i < 4; ++i)
#pragma unroll
        for (int j = 0; j < 4; ++j)
          acc[i][j] = MFMA16(af[i][ks], bfr[j][ks], acc[i][j]);
  }

  const float* bias = seg == 0 ? bq : seg == 1 ? bk : bv;
  const float scale = seg == 0 ? QSCALE : 1.0f;
  bf16* dst01 = seg == 0 ? Qb : Kb;
#pragma unroll
  for (int i = 0; i < 4; ++i) {
    const int m = m0 + wm * 64 + i * 16 + quad * 4;
#pragma unroll
    for (int j = 0; j < 4; ++j) {
      const int nn = n0 + wn * 64 + j * 16 + r;
      const float bv_ = bias[nn];
      if (seg == 2) {                       // V: transposed packed store
        short4v pk;
        *(__hip_bfloat162*)&pk = __float22bfloat162_rn(
            float2{acc[i][j][0] + bv_, acc[i][j][1] + bv_});
        *((__hip_bfloat162*)&pk + 1) = __float22bfloat162_rn(
            float2{acc[i][j][2] + bv_, acc[i][j][3] + bv_});
        *(short4v*)(Vtg + (size_t)nn * 4096 + m) = pk;
      } else {
#pragma unroll
        for (int g = 0; g < 4; ++g)
          dst01[(size_t)(m + g) * 1024 + nn] =
              __float2bfloat16((acc[i][j][g] + bv_) * scale);
      }
    }
  }
}

// ---------------- proj GEMM: out[4096,1024] = Ob @ Wo^T + bo (f32 out) -------
// grid 512 (1-D, XCD-partitioned): each XCD owns one 128-col B-panel.
__global__ __launch_bounds__(256) void proj_kernel(const bf16* __restrict__ X,
                                                   const bf16* __restrict__ W,
                                                   const float* __restrict__ bias,
                                                   float* __restrict__ Y) {
  constexpr int K = 1024, N = 1024;
  __shared__ bf16 As[64 * 64];
  __shared__ bf16 Bs[128 * 64];
  const int t = threadIdx.x;
  const int lane = t & 63, w = t >> 6;
  const int quad = lane >> 4, r = lane & 15;
  const int bid = blockIdx.x;               // 0..511
  const int xcd = bid & 7, idx = bid >> 3;  // idx 0..63
  const int m0 = idx * 64, n0 = xcd * 128;
  const int wm = w >> 1, wn = w & 1;

  f32x4 acc[2][4] = {};

  for (int k0 = 0; k0 < K; k0 += 64) {
    __syncthreads();
#pragma unroll
    for (int p = 0; p < 2; ++p) {           // A: 512 chunks
      const int c = p * 256 + w * 64 + lane;
      const int row = c >> 3;
      const int scb = (c & 7) ^ (row & 7);
      load_lds16(X + (size_t)(m0 + row) * K + k0 + scb * 8, As + c * 8);
    }
#pragma unroll
    for (int p = 0; p < 4; ++p) {           // B: 1024 chunks
      const int c = p * 256 + w * 64 + lane;
      const int row = c >> 3;
      const int scb = (c & 7) ^ (row & 7);
      load_lds16(W + (size_t)(n0 + row) * K + k0 + scb * 8, Bs + c * 8);
    }
    __syncthreads();
    short8 af[2][2], bfr[4][2];
#pragma unroll
    for (int ks = 0; ks < 2; ++ks) {
#pragma unroll
      for (int i = 0; i < 2; ++i) {
        const int ra = wm * 32 + i * 16 + r;
        af[i][ks] = *(const short8*)(As + ra * 64 +
                                     (((ks * 4 + quad) ^ (ra & 7)) * 8));
      }
#pragma unroll
      for (int j = 0; j < 4; ++j) {
        const int rb = wn * 64 + j * 16 + r;
        bfr[j][ks] = *(const short8*)(Bs + rb * 64 +
                                      (((ks * 4 + quad) ^ (rb & 7)) * 8));
      }
    }
#pragma unroll
    for (int ks = 0; ks < 2; ++ks)
#pragma unroll
      for (int i = 0; i < 2; ++i)
#pragma unroll
        for (int j = 0; j < 4; ++j)
          acc[i][j] = MFMA16(af[i][ks], bfr[j][ks], acc[i][j]);
  }
#pragma unroll
  for (int i = 0; i < 2; ++i) {
    const int m = m0 + wm * 32 + i * 16 + quad * 4;
#pragma unroll
    for (int j = 0; j < 4; ++j) {
      const int n = n0 + wn * 64 + j * 16 + r;
      const float bv = bias[n];
#pragma unroll
      for (int g = 0; g < 4; ++g)
        Y[(size_t)(m + g) * N + n] = acc[i][j][g] + bv;
    }
  }
}

// ---------------- Flash attention v9: unpaired, CU-balanced, 4 groups/CU -----
// grid 1024 x 256 thr (4 waves: qs = w&1 32-q strip, kst = w>>1 32-key
// strip). Decode (round-robin dispatch bid%8->XCD, (bid>>3)%32->CU):
// x=bid&7, u=(bid>>3)&31, k=bid>>8; group g = x+8k (h=g&15, b=g>>4);
// j = {u, 31-u, (u+8)&31, 31-((u+8)&31)}[k] -> each CU's 4 blocks sum to
// 66 tiles, each (h,b) on one XCD. LDS 32KB = K[2][64x64] + V[2][64x64];
// stage tile s+1 while computing s, vmcnt(4) BEFORE the barrier (safe).
// Per wave-step: 8 ds_read_b128, 16 MFMA (ratio 0.5); register P via
// permlane merge; 2-way kst combine at the end.
__global__ __launch_bounds__(256, 4) void attn_kernel(const bf16* __restrict__ Qb,
                                                      const bf16* __restrict__ Kb,
                                                      const bf16* __restrict__ Vtg,
                                                      bf16* __restrict__ Ob) {
  const int bid = blockIdx.x;
  const int x = bid & 7, u = (bid >> 3) & 31, k = bid >> 8;
  const int g = x + 8 * k;                  // 0..31
  const int h = g & 15, b = g >> 4;
  const int u8 = (u + 8) & 31;
  const int j = (k == 0) ? u : (k == 1) ? 31 - u : (k == 2) ? u8 : 31 - u8;
  const int T = j + 1;

  const int t = threadIdx.x;
  const int lane = t & 63, w = t >> 6;
  const int qs = w & 1, kst = w >> 1;
  const int quad = lane >> 4, r = lane & 15;

  __shared__ __align__(16) bf16 smem[16384]; // 32KB: K[2][4096] | V[2][4096]

  // staging geometry: 256 threads x 2 chunks per 8KB tile array
  const bf16 *kg[2], *vg[2];
  int lofs[2];
#pragma unroll
  for (int p = 0; p < 2; ++p) {
    const int c = p * 256 + t;
    const int row = c >> 3, scb = (c & 7) ^ (row & 7);
    kg[p] = Kb + (size_t)(b * 2048 + row) * 1024 + h * 64 + scb * 8;
    vg[p] = Vtg + (size_t)(h * 64 + row) * 4096 + (size_t)b * 2048 + scb * 8;
    lofs[p] = c * 8;
  }

  auto stage_tile = [&](int tile, int slot) {
    bf16* const kd = smem + slot * 4096;
    bf16* const vd = smem + 8192 + slot * 4096;
#pragma unroll
    for (int p = 0; p < 2; ++p)
      load_lds16(kg[p] + (size_t)tile * 65536, kd + lofs[p]);
#pragma unroll
    for (int p = 0; p < 2; ++p)
      load_lds16(vg[p] + tile * 64, vd + lofs[p]);
  };

  // Q fragments (B-operand): [qfr][ks]
  short8 qf[2][2];
#pragma unroll
  for (int qfr = 0; qfr < 2; ++qfr)
#pragma unroll
    for (int ks = 0; ks < 2; ++ks)
      qf[qfr][ks] = *(const short8*)(
          Qb + (size_t)(b * 2048 + j * 64 + qs * 32 + qfr * 16 + r) * 1024 +
          h * 64 + ks * 32 + quad * 8);

  f32x4 o[4][2] = {};                       // [mt(d)][qfr]
  float lsum[2] = {0.f, 0.f};

  stage_tile(0, 0);
  for (int s = 0; s < T; ++s) {
    if (s + 1 < T) {
      stage_tile(s + 1, (s + 1) & 1);
      asm volatile("s_waitcnt vmcnt(4)" ::: "memory");  // tile s landed
    } else {
      asm volatile("s_waitcnt vmcnt(0)" ::: "memory");
    }
    __builtin_amdgcn_s_barrier();
    __builtin_amdgcn_sched_barrier(0);

    const bf16* const ksb = smem + (s & 1) * 4096;
    const bf16* const vtb = smem + 8192 + (s & 1) * 4096;

    __builtin_amdgcn_s_setprio(1);
    // ---- S^T = K * Q^T : this wave's 32-key strip x 32 q ----
    short8 kf[2][2];
#pragma unroll
    for (int mt2 = 0; mt2 < 2; ++mt2) {
      const int krow = kst * 32 + mt2 * 16 + r;
#pragma unroll
      for (int ks = 0; ks < 2; ++ks)
        kf[mt2][ks] = *(const short8*)(ksb + krow * 64 +
                                       (((ks * 4 + quad) ^ (r & 7)) * 8));
    }
    f32x4 st[2][2] = {};
#pragma unroll
    for (int mt2 = 0; mt2 < 2; ++mt2)
#pragma unroll
      for (int qfr = 0; qfr < 2; ++qfr) {
        st[mt2][qfr] = MFMA16(kf[mt2][0], qf[qfr][0], st[mt2][qfr]);
        st[mt2][qfr] = MFMA16(kf[mt2][1], qf[qfr][1], st[mt2][qfr]);
      }
    if (s == T - 1) {                       // diagonal tile mask
#pragma unroll
      for (int mt2 = 0; mt2 < 2; ++mt2)
#pragma unroll
        for (int qfr = 0; qfr < 2; ++qfr) {
          const int kb2 = s * 64 + kst * 32 + mt2 * 16 + quad * 4;
          const int qrow = j * 64 + qs * 32 + qfr * 16 + r;
#pragma unroll
          for (int g4 = 0; g4 < 4; ++g4)
            if (kb2 + g4 > qrow) st[mt2][qfr][g4] = -1e30f;
        }
    }
    // ---- softmax numerators + pack ----
    unsigned cpk[2][2][2];                  // [mt2][qfr][pair]
#pragma unroll
    for (int mt2 = 0; mt2 < 2; ++mt2)
#pragma unroll
      for (int qfr = 0; qfr < 2; ++qfr) {
        const float p0 = __builtin_amdgcn_exp2f(st[mt2][qfr][0]);
        const float p1 = __builtin_amdgcn_exp2f(st[mt2][qfr][1]);
        const float p2 = __builtin_amdgcn_exp2f(st[mt2][qfr][2]);
        const float p3 = __builtin_amdgcn_exp2f(st[mt2][qfr][3]);
        lsum[qfr] += (p0 + p1) + (p2 + p3);
        unsigned u0, u1;
        *(__hip_bfloat162*)&u0 = __float22bfloat162_rn(float2{p0, p1});
        *(__hip_bfloat162*)&u1 = __float22bfloat162_rn(float2{p2, p3});
        cpk[mt2][qfr][0] = u0;
        cpk[mt2][qfr][1] = u1;
      }
    // ---- register P -> PV B-fragment (verified permlane merge) ----
    short8 pf[2];
#pragma unroll
    for (int qfr = 0; qfr < 2; ++qfr) {
      unsigned br[4];
#pragma unroll
      for (int p2 = 0; p2 < 2; ++p2) {
        uint2v s32 = __builtin_amdgcn_permlane32_swap(
            cpk[0][qfr][p2], cpk[1][qfr][p2], false, false);
        uint2v s16 = __builtin_amdgcn_permlane16_swap(s32.x, s32.y,
                                                      false, false);
        br[p2] = s16.x; br[p2 + 2] = s16.y;
      }
      uint4v pv_; pv_.x = br[0]; pv_.y = br[1]; pv_.z = br[2]; pv_.w = br[3];
      pf[qfr] = __builtin_bit_cast(short8, pv_);
    }
    // ---- PV: O^T += V^T * P over this wave's 32 keys (K=32) ----
#pragma unroll
    for (int mt = 0; mt < 4; ++mt) {
      const short8 vf = *(const short8*)(vtb + (mt * 16 + r) * 64 +
                                         (((kst * 4 + quad) ^ (r & 7)) * 8));
#pragma unroll
      for (int qfr = 0; qfr < 2; ++qfr)
        o[mt][qfr] = MFMA16(vf, pf[qfr], o[mt][qfr]);
    }
    __builtin_amdgcn_s_setprio(0);
    __builtin_amdgcn_sched_barrier(0);
    __builtin_amdgcn_s_barrier();           // slot (s+1)&1 free for restage
  }

  // ---- combine the 2 key-strips (one LDS round, reuses K/V regions) ----
#pragma unroll
  for (int qfr = 0; qfr < 2; ++qfr) {
    lsum[qfr] += __shfl_xor(lsum[qfr], 16);
    lsum[qfr] += __shfl_xor(lsum[qfr], 32);
  }
  __syncthreads();
  f32x4* const cb = (f32x4*)smem;           // [qs][qfr][mt][lane] = 16KB
  float* const lb = (float*)(smem + 8192);  // [qs][qfr][lane] = 1KB (V area)
  if (kst == 1) {
#pragma unroll
    for (int mt = 0; mt < 4; ++mt)
#pragma unroll
      for (int qfr = 0; qfr < 2; ++qfr)
        cb[((qs * 2 + qfr) * 4 + mt) * 64 + lane] = o[mt][qfr];
#pragma unroll
    for (int qfr = 0; qfr < 2; ++qfr)
      lb[(qs * 2 + qfr) * 64 + lane] = lsum[qfr];
  }
  __syncthreads();
  if (kst == 0) {
    float inv[2];
#pragma unroll
    for (int qfr = 0; qfr < 2; ++qfr)
      inv[qfr] = 1.f / (lsum[qfr] + lb[(qs * 2 + qfr) * 64 + lane]);
#pragma unroll
    for (int mt = 0; mt < 4; ++mt)
#pragma unroll
      for (int qfr = 0; qfr < 2; ++qfr) {
        const f32x4 a = cb[((qs * 2 + qfr) * 4 + mt) * 64 + lane];
        short4v ph;
        *(__hip_bfloat162*)&ph = __float22bfloat162_rn(
            float2{(o[mt][qfr][0] + a[0]) * inv[qfr],
                   (o[mt][qfr][1] + a[1]) * inv[qfr]});
        *((__hip_bfloat162*)&ph + 1) = __float22bfloat162_rn(
            float2{(o[mt][qfr][2] + a[2]) * inv[qfr],
                   (o[mt][qfr][3] + a[3]) * inv[qfr]});
        *(short4v*)(Ob +
            (size_t)(b * 2048 + j * 64 + qs * 32 + qfr * 16 + r) * 1024 +
            h * 64 + mt * 16 + quad * 4) = ph;
      }
  }
}

extern "C" void kernel_launch(void* const* d_in, const int* in_sizes, int n_in,
                              void* d_out, int out_size, void* d_ws, size_t ws_size,
                              hipStream_t stream) {
  const float* x  = (const float*)d_in[0];
  const float* Wq = (const float*)d_in[1];
  const float* bq = (const float*)d_in[2];
  const float* Wk = (const float*)d_in[3];
  const float* bk = (const float*)d_in[4];
  const float* Wv = (const float*)d_in[5];
  const float* bv = (const float*)d_in[6];
  const float* Wo = (const float*)d_in[7];
  const float* bo = (const float*)d_in[8];
  float* out = (float*)d_out;

  bf16* xb   = (bf16*)d_ws;                     // 4M elems
  bf16* wcat = xb + (size_t)4096 * 1024;        // [wq|wk|wv|wo]
  bf16* wob  = wcat + (size_t)3 * 1024 * 1024;
  bf16* Qb   = wcat + (size_t)4 * 1024 * 1024;
  bf16* Kb   = Qb  + (size_t)4096 * 1024;
  bf16* Vtg  = Kb  + (size_t)4096 * 1024;       // V^T [1024][4096]
  bf16* Ob   = Vtg + (size_t)4096 * 1024;
  const size_t need = ((size_t)4096 * 1024 * 5 + (size_t)1024 * 1024 * 4) * 2;
  if (ws_size < need) return;

  cvt_kernel<<<8192, 256, 0, stream>>>(x, Wq, Wk, Wv, Wo, xb, wcat);
  qkv_kernel<<<768, 256, 0, stream>>>(xb, wcat, bq, bk, bv, Qb, Kb, Vtg);
  attn_kernel<<<1024, 256, 0, stream>>>(Qb, Kb, Vtg, Ob);
  proj_kernel<<<512, 256, 0, stream>>>(Ob, wob, bo, out);
}